// Round 9
// baseline (178.475 us; speedup 1.0000x reference)
//
#include <hip/hip_runtime.h>

// NodeClassifier 3-layer MP-GNN, MI355X. R9: break the VGPR-64 occupancy cliff.
// R8 post-mortem: layer_kernel @68 VGPR -> 16 waves/CU regardless of block
// shape (waves/CU halves at vgpr=64). Fix: no LDS B-staging (load B fragments
// direct from global; W is L2-resident), LDS 35.9->14.8KB, launch_bounds(256,8)
// to force VGPR<=64 -> 8 blocks/CU = 32 waves/CU during gather.
// 5 dispatches: prep, place, L1 fused, L2 fused + chained L3, agg40.
// agg(x@W+b) == agg(x)@W + deg*b. Lessons: grid.sync ~35us (R3); single-block
// serial work = straggler (R4); dispatch overhead ~8-10us each.

#define N_NODES   10000
#define N_EDGES   320000
#define D_HID     256
#define N_CLASSES 40
#define CAP       96

typedef __attribute__((ext_vector_type(8))) short short8;
typedef __attribute__((ext_vector_type(4))) float f32x4;

__device__ __forceinline__ ushort f2bf(float f) {
    unsigned u = __float_as_uint(f);
    u = (u + 0x7fffu + ((u >> 16) & 1u)) >> 16;   // RNE; inputs finite
    return (ushort)u;
}
__device__ __forceinline__ float bf2f(ushort u) {
    return __uint_as_float(((unsigned)u) << 16);
}

// ---------------- prep: zero cursor, pad rows, bf16 conversions ----------------

__global__ __launch_bounds__(256)
void prep_kernel(const float* __restrict__ X,
                 const float* __restrict__ W1, const float* __restrict__ W2,
                 const float* __restrict__ W3,
                 ushort* __restrict__ Xb, ushort* __restrict__ bufY,
                 ushort* __restrict__ bufH,
                 ushort* __restrict__ W1b, ushort* __restrict__ W2b,
                 ushort* __restrict__ W3b, int* __restrict__ cursor) {
    const int tid  = blockIdx.x * 256 + threadIdx.x;
    const int nthr = gridDim.x * 256;
    for (int i = tid; i < N_NODES; i += nthr) cursor[i] = 0;
    // zero the padding rows (node index N_NODES used by clamp-select)
    ushort4 z; z.x = 0; z.y = 0; z.z = 0; z.w = 0;
    if (tid < 64) {
        ((ushort4*)Xb)[640000 + tid]   = z;   // row 10000 of Xb
        ((ushort4*)bufY)[640000 + tid] = z;   // row 10000 of bufY
    }
    if (tid < 10) ((ushort4*)bufH)[100000 + tid] = z;  // row 10000 of bufH
    // X -> bf16
    for (int i = tid; i < N_NODES * D_HID / 4; i += nthr) {
        float4 v = ((const float4*)X)[i];
        ushort4 o;
        o.x = f2bf(v.x); o.y = f2bf(v.y); o.z = f2bf(v.z); o.w = f2bf(v.w);
        ((ushort4*)Xb)[i] = o;
    }
    // weights -> bf16, transposed to n-major
    for (int i = tid; i < 141312; i += nthr) {
        if (i < 65536) {
            int n = i >> 8, k = i & 255;
            W1b[i] = f2bf(W1[k * 256 + n]);
        } else if (i < 131072) {
            int t2 = i - 65536;
            int n = t2 >> 8, k = t2 & 255;
            W2b[t2] = f2bf(W2[k * 256 + n]);
        } else {
            int t2 = i - 131072;
            int n = t2 >> 8, k = t2 & 255;
            W3b[t2] = f2bf(W3[k * N_CLASSES + n]);
        }
    }
}

// ---------------- place: bucket CSR via global atomics ----------------

__global__ __launch_bounds__(256)
void place_kernel(const int* __restrict__ edges, int* __restrict__ cursor,
                  int* __restrict__ esrc) {
    int e = blockIdx.x * 256 + threadIdx.x;
    if (e < N_EDGES) {
        int d = edges[N_EDGES + e];
        int pos = atomicAdd(&cursor[d], 1);
        if (pos < CAP) esrc[d * CAP + pos] = edges[e];
    }
}

// ---------------- fused layer: agg(16 nodes) -> LDS -> MFMA GEMM -> relu ----------------
// 256 threads = 4 waves, 16 nodes/block (4 per wave), 625 blocks.
// No LDS B-staging: B fragments loaded direct from global (W is L2-resident).
// LDS ~14.8KB + VGPR<=64 -> 8 blocks/CU = 32 waves/CU for the gather phase.
// GEMM: wave w -> cols w*64..+64, 4 MFMA/k-step, no barriers inside the loop.
// CHAIN: out2 tile stays in LDS -> @W3(global) + b3 -> h3.

#define LDSA 264   // padded LDS row stride (bf16)

template<bool CHAIN>
__global__ __launch_bounds__(256, 8)
void layer_kernel(const ushort* __restrict__ Xin, const ushort* __restrict__ Bt,
                  const float* __restrict__ bias,
                  const int* __restrict__ deg, const int* __restrict__ esrc,
                  const ushort* __restrict__ W3b, const float* __restrict__ b3,
                  ushort* __restrict__ Out) {
    __shared__ ushort As[16 * LDSA];      // 8448 B; x_agg, reused as out2 when CHAIN
    __shared__ int    eidxL[16 * CAP];    // 6144 B
    __shared__ int    degI[16];
    __shared__ float  degF[16];

    const int tid = threadIdx.x;
    const int wave = tid >> 6, lane = tid & 63;
    const int lr = lane & 15, lg = lane >> 4;
    const int rowBase = blockIdx.x * 16;

    // ---- phase 0: stage edge lists + degrees ----
#pragma unroll
    for (int p = 0; p < 6; ++p) {
        int idx = p * 256 + tid;          // 16*96 = 1536 ints
        eidxL[idx] = esrc[rowBase * CAP + idx];
    }
    if (tid < 16) {
        int c = deg[rowBase + tid];
        degF[tid] = (float)c;             // true degree (bias term)
        degI[tid] = (c > CAP) ? CAP : c;
    }
    __syncthreads();

    // ---- phase 1: gather (4 nodes per wave, batches of 8, clamp-select) ----
    const uint2* hp = (const uint2*)Xin;
#pragma unroll 1
    for (int it = 0; it < 4; ++it) {
        int nl = wave * 4 + it;
        const int cnt  = degI[nl];
        const int cntp = (cnt + 7) & ~7;
        float a0 = 0.f, a1 = 0.f, a2 = 0.f, a3 = 0.f;
#pragma unroll 1
        for (int i = 0; i < cntp; i += 8) {
            uint2 v[8];
#pragma unroll
            for (int u = 0; u < 8; ++u) {
                int slot = i + u;
                int s = (slot < cnt) ? eidxL[nl * CAP + slot] : N_NODES;
                v[u] = hp[(size_t)s * 64 + lane];
            }
#pragma unroll
            for (int u = 0; u < 8; ++u) {
                a0 += bf2f((ushort)(v[u].x & 0xffff));
                a1 += bf2f((ushort)(v[u].x >> 16));
                a2 += bf2f((ushort)(v[u].y & 0xffff));
                a3 += bf2f((ushort)(v[u].y >> 16));
            }
        }
        uint2 o;
        o.x = (unsigned)f2bf(a0) | ((unsigned)f2bf(a1) << 16);
        o.y = (unsigned)f2bf(a2) | ((unsigned)f2bf(a3) << 16);
        *(uint2*)(As + nl * LDSA + lane * 4) = o;
    }
    __syncthreads();

    // ---- phase 2: GEMM 16x256 @ 256x256; B fragments direct from global ----
    f32x4 acc[4] = {};
#pragma unroll 1
    for (int k0 = 0; k0 < 256; k0 += 32) {
        short8 af = *(const short8*)(As + lr * LDSA + k0 + lg * 8);
#pragma unroll
        for (int j = 0; j < 4; ++j) {
            int col = wave * 64 + j * 16 + lr;
            short8 bf = *(const short8*)(Bt + (size_t)col * 256 + k0 + lg * 8);
            acc[j] = __builtin_amdgcn_mfma_f32_16x16x32_bf16(af, bf, acc[j], 0, 0, 0);
        }
    }

    if (!CHAIN) {
        // epilogue: relu(acc + deg*b) -> bf16 global (625*16 = 10000, no mask)
#pragma unroll
        for (int j = 0; j < 4; ++j) {
            int col = wave * 64 + j * 16 + lr;
            float bv = bias[col];
#pragma unroll
            for (int r = 0; r < 4; ++r) {
                int grow = rowBase + lg * 4 + r;
                float dg = degF[lg * 4 + r];
                Out[(size_t)grow * 256 + col] = f2bf(fmaxf(fmaf(dg, bv, acc[j][r]), 0.f));
            }
        }
    } else {
        __syncthreads();   // all As reads done before overwrite
        // out2 tile -> As (bf16), cols disjoint per wave
#pragma unroll
        for (int j = 0; j < 4; ++j) {
            int col = wave * 64 + j * 16 + lr;
            float bv = bias[col];
#pragma unroll
            for (int r = 0; r < 4; ++r) {
                int rl = lg * 4 + r;
                As[rl * LDSA + col] = f2bf(fmaxf(fmaf(degF[rl], bv, acc[j][r]), 0.f));
            }
        }
        __syncthreads();
        // gemm3: h3 = out2 @ W3 + b3; W3 fragments direct from global (20KB, L2)
        if (wave < 3) {
            int col = wave * 16 + lr;
            int colc = (col < N_CLASSES) ? col : 0;   // clamp for load safety
            f32x4 acc3 = {};
#pragma unroll 1
            for (int k0 = 0; k0 < 256; k0 += 32) {
                short8 af = *(const short8*)(As + lr * LDSA + k0 + lg * 8);
                short8 bf = *(const short8*)(W3b + (size_t)colc * 256 + k0 + lg * 8);
                acc3 = __builtin_amdgcn_mfma_f32_16x16x32_bf16(af, bf, acc3, 0, 0, 0);
            }
            if (col < N_CLASSES) {
                float bv = b3[col];
#pragma unroll
                for (int r = 0; r < 4; ++r) {
                    int grow = rowBase + lg * 4 + r;
                    Out[(size_t)grow * N_CLASSES + col] = f2bf(acc3[r] + bv);
                }
            }
        }
    }
}

// ---------------- agg40: out = relu(segsum(h3[src])) -> f32 ----------------

__global__ __launch_bounds__(256)
void agg_relu_40_kernel(const ushort* __restrict__ h, const int* __restrict__ deg,
                        const int* __restrict__ esrc, float* __restrict__ out) {
    int wv   = threadIdx.x >> 6;
    int lane = threadIdx.x & 63;
    int node = (blockIdx.x << 2) + wv;
    if (node >= N_NODES) return;
    int cnt = deg[node];
    if (cnt > CAP) cnt = CAP;
    int cntp = (cnt + 7) & ~7;
    const int* ep = esrc + node * CAP;
    if (lane < N_CLASSES) {
        float a = 0.f, b = 0.f;
#pragma unroll 1
        for (int i = 0; i < cntp; i += 8) {
            int s[8];
#pragma unroll
            for (int u = 0; u < 8; ++u) s[u] = (i + u < cnt) ? ep[i + u] : N_NODES;
#pragma unroll
            for (int u = 0; u < 8; u += 2) {
                a += bf2f(h[(size_t)s[u]     * N_CLASSES + lane]);
                b += bf2f(h[(size_t)s[u + 1] * N_CLASSES + lane]);
            }
        }
        out[(size_t)node * N_CLASSES + lane] = fmaxf(a + b, 0.f);
    }
}

// ---------------- launch ----------------

extern "C" void kernel_launch(void* const* d_in, const int* in_sizes, int n_in,
                              void* d_out, int out_size, void* d_ws, size_t ws_size,
                              hipStream_t stream) {
    const float* X     = (const float*)d_in[0];
    const int*   edges = (const int*)d_in[1];
    const float* W1 = (const float*)d_in[2];
    const float* b1 = (const float*)d_in[3];
    const float* W2 = (const float*)d_in[4];
    const float* b2 = (const float*)d_in[5];
    const float* W3 = (const float*)d_in[6];
    const float* b3 = (const float*)d_in[7];
    float* out = (float*)d_out;

    char* ws = (char*)d_ws;
    ushort* Xb   = (ushort*)(ws);                    //  5,120,512 B (10001 rows x 256)
    ushort* bufY = (ushort*)(ws + 5120512);          //  5,120,512 B (10001 rows)
    ushort* bufH = (ushort*)(ws + 10241024);         //    800,080 B (10001 rows x 40)
    ushort* W1b  = (ushort*)(ws + 11041104);         //    131,072 B (n-major)
    ushort* W2b  = (ushort*)(ws + 11172176);         //    131,072 B
    ushort* W3b  = (ushort*)(ws + 11303248);         //     20,480 B
    int*   cursor = (int*)(ws + 11323728);           //     40,000 B (== deg after place)
    int*   esrc   = (int*)(ws + 11363728);           //  3,840,000 B (10000 x 96)

    // 1: conversions + zero cursor + zero pad rows
    prep_kernel<<<512, 256, 0, stream>>>(X, W1, W2, W3, Xb, bufY, bufH,
                                         W1b, W2b, W3b, cursor);
    // 2: bucket-CSR place
    place_kernel<<<(N_EDGES + 255) / 256, 256, 0, stream>>>(edges, cursor, esrc);
    // 3: layer 1 fused (agg + GEMM + relu)
    layer_kernel<false><<<N_NODES / 16, 256, 0, stream>>>(
        Xb, W1b, b1, cursor, esrc, W3b, b3, bufY);
    // 4: layer 2 fused + chained layer-3 transform (h3 = out2@W3 + b3)
    layer_kernel<true><<<N_NODES / 16, 256, 0, stream>>>(
        bufY, W2b, b2, cursor, esrc, W3b, b3, bufH);
    // 5: final aggregation + relu -> d_out (f32)
    agg_relu_40_kernel<<<(N_NODES + 3) / 4, 256, 0, stream>>>(bufH, cursor, esrc, out);
}

// Round 10
// 173.925 us; speedup vs baseline: 1.0262x; 1.0262x over previous
//
#include <hip/hip_runtime.h>

// NodeClassifier 3-layer MP-GNN, MI355X. R10: revert to R7 structure (best,
// 160us) + fix the two counter-backed inefficiencies:
//   (1) Bs staging bank conflicts (681K cycles in R6): stride 40 -> 44 ushorts.
//   (2) prep W-transpose uncoalesced reads: 64x64 LDS-tile transpose.
// Keep clamp-select gather (no esrc dummy fill), plain launch_bounds(256).
// R8 lesson: gather is BW-bound past ~16 waves/CU (bigger blocks = no gain).
// R9 lesson: forcing min-waves causes spills; B-direct-from-global exposes
// L2 latency to the MFMA loop. 5 dispatches; agg(x@W+b) == agg(x)@W + deg*b.

#define N_NODES   10000
#define N_EDGES   320000
#define D_HID     256
#define N_CLASSES 40
#define CAP       96

typedef __attribute__((ext_vector_type(8))) short short8;
typedef __attribute__((ext_vector_type(4))) float f32x4;

__device__ __forceinline__ ushort f2bf(float f) {
    unsigned u = __float_as_uint(f);
    u = (u + 0x7fffu + ((u >> 16) & 1u)) >> 16;   // RNE; inputs finite
    return (ushort)u;
}
__device__ __forceinline__ float bf2f(ushort u) {
    return __uint_as_float(((unsigned)u) << 16);
}

// ---------------- prep: zero cursor, pad rows, bf16 conversions ----------------
// Blocks 0..31: coalesced 64x64 LDS-tile transpose of W1/W2 (f32 -> bf16 n-major).
// Blocks 32+: grid-stride X conversion, W3 transpose (small), cursor zero, pads.

__global__ __launch_bounds__(256)
void prep_kernel(const float* __restrict__ X,
                 const float* __restrict__ W1, const float* __restrict__ W2,
                 const float* __restrict__ W3,
                 ushort* __restrict__ Xb, ushort* __restrict__ bufY,
                 ushort* __restrict__ bufH,
                 ushort* __restrict__ W1b, ushort* __restrict__ W2b,
                 ushort* __restrict__ W3b, int* __restrict__ cursor) {
    __shared__ float tile[64][65];
    const int tid = threadIdx.x;
    if (blockIdx.x < 32) {
        // W1 (blocks 0..15) / W2 (16..31): tile (k0,n0) of the 256x256 matrix
        const float* W  = (blockIdx.x < 16) ? W1 : W2;
        ushort* Wb      = (blockIdx.x < 16) ? W1b : W2b;
        const int b  = blockIdx.x & 15;
        const int k0 = (b >> 2) * 64, n0 = (b & 3) * 64;
        const int lane64 = tid & 63, quad = tid >> 6;
#pragma unroll
        for (int i = 0; i < 16; ++i) {
            int kl = quad + i * 4;
            tile[lane64][kl] = W[(size_t)(k0 + kl) * 256 + n0 + lane64];  // coalesced read
        }
        __syncthreads();
#pragma unroll
        for (int i = 0; i < 16; ++i) {
            int nl = quad + i * 4;
            Wb[(size_t)(n0 + nl) * 256 + k0 + lane64] = f2bf(tile[nl][lane64]);  // coalesced write
        }
        return;
    }
    const int tid0 = (blockIdx.x - 32) * 256 + tid;
    const int nthr = (gridDim.x - 32) * 256;
    for (int i = tid0; i < N_NODES; i += nthr) cursor[i] = 0;
    // zero padding rows (node index N_NODES is the clamp-select target)
    ushort4 z; z.x = 0; z.y = 0; z.z = 0; z.w = 0;
    if (tid0 < 64) {
        ((ushort4*)Xb)[640000 + tid0]   = z;   // row 10000 of Xb
        ((ushort4*)bufY)[640000 + tid0] = z;   // row 10000 of bufY
    }
    if (tid0 < 10) ((ushort4*)bufH)[100000 + tid0] = z;  // row 10000 of bufH
    // X -> bf16
    for (int i = tid0; i < N_NODES * D_HID / 4; i += nthr) {
        float4 v = ((const float4*)X)[i];
        ushort4 o;
        o.x = f2bf(v.x); o.y = f2bf(v.y); o.z = f2bf(v.z); o.w = f2bf(v.w);
        ((ushort4*)Xb)[i] = o;
    }
    // W3 (256x40) -> bf16 n-major (small; scalar is fine)
    for (int i = tid0; i < N_CLASSES * 256; i += nthr) {
        int n = i >> 8, k = i & 255;
        W3b[i] = f2bf(W3[(size_t)k * N_CLASSES + n]);
    }
}

// ---------------- place: bucket CSR via global atomics ----------------

__global__ __launch_bounds__(256)
void place_kernel(const int* __restrict__ edges, int* __restrict__ cursor,
                  int* __restrict__ esrc) {
    int e = blockIdx.x * 256 + threadIdx.x;
    if (e < N_EDGES) {
        int d = edges[N_EDGES + e];
        int pos = atomicAdd(&cursor[d], 1);
        if (pos < CAP) esrc[d * CAP + pos] = edges[e];
    }
}

// ---------------- fused layer: agg(16 nodes) -> LDS -> MFMA GEMM -> relu ----------------
// 256 threads = 4 waves, 16 nodes/block (4 per wave), 625 blocks.
// Phase 1: wave-per-node gather, batches of 8, clamp-select (no tail).
// Phase 2: GEMM 16x256 @ 256x256; Bs staged per 32-k slice, stride 44 (no
// 8-way staging conflicts); wave w -> cols w*64..+64, 4 MFMA/k-step.
// CHAIN: out2 tile stays in LDS -> @W3 + b3 -> h3 global (waves 0..2).

#define LDSA 264   // As row stride (bf16)
#define LDSB 44    // Bs row stride (bf16): 22 dwords -> ~2-way max on b128 ops

template<bool CHAIN>
__global__ __launch_bounds__(256)
void layer_kernel(const ushort* __restrict__ Xin, const ushort* __restrict__ Bt,
                  const float* __restrict__ bias,
                  const int* __restrict__ deg, const int* __restrict__ esrc,
                  const ushort* __restrict__ W3b, const float* __restrict__ b3,
                  ushort* __restrict__ Out) {
    __shared__ ushort As[16 * LDSA];      //  8448 B; x_agg, reused as out2 when CHAIN
    __shared__ ushort Bs[256 * LDSB];     // 22528 B; main: [256 n][44-stride]; chain: W3 [40][264]
    __shared__ int    eidxL[16 * CAP];    //  6144 B
    __shared__ int    degI[16];
    __shared__ float  degF[16];

    const int tid = threadIdx.x;
    const int wave = tid >> 6, lane = tid & 63;
    const int lr = lane & 15, lg = lane >> 4;
    const int rowBase = blockIdx.x * 16;

    // ---- phase 0: stage edge lists + degrees ----
#pragma unroll
    for (int p = 0; p < 6; ++p) {
        int idx = p * 256 + tid;          // 16*96 = 1536 ints
        eidxL[idx] = esrc[rowBase * CAP + idx];
    }
    if (tid < 16) {
        int c = deg[rowBase + tid];
        degF[tid] = (float)c;             // true degree (bias term)
        degI[tid] = (c > CAP) ? CAP : c;
    }
    __syncthreads();

    // ---- phase 1: gather (4 nodes per wave, batches of 8, clamp-select) ----
    const uint2* hp = (const uint2*)Xin;
#pragma unroll 1
    for (int it = 0; it < 4; ++it) {
        int nl = wave * 4 + it;
        const int cnt  = degI[nl];
        const int cntp = (cnt + 7) & ~7;
        float a0 = 0.f, a1 = 0.f, a2 = 0.f, a3 = 0.f;
#pragma unroll 1
        for (int i = 0; i < cntp; i += 8) {
            uint2 v[8];
#pragma unroll
            for (int u = 0; u < 8; ++u) {
                int slot = i + u;
                int s = (slot < cnt) ? eidxL[nl * CAP + slot] : N_NODES;
                v[u] = hp[(size_t)s * 64 + lane];
            }
#pragma unroll
            for (int u = 0; u < 8; ++u) {
                a0 += bf2f((ushort)(v[u].x & 0xffff));
                a1 += bf2f((ushort)(v[u].x >> 16));
                a2 += bf2f((ushort)(v[u].y & 0xffff));
                a3 += bf2f((ushort)(v[u].y >> 16));
            }
        }
        uint2 o;
        o.x = (unsigned)f2bf(a0) | ((unsigned)f2bf(a1) << 16);
        o.y = (unsigned)f2bf(a2) | ((unsigned)f2bf(a3) << 16);
        *(uint2*)(As + nl * LDSA + lane * 4) = o;
    }

    // ---- phase 2: GEMM 16x256 @ 256x256 ----
    f32x4 acc[4] = {};
    for (int k0 = 0; k0 < 256; k0 += 32) {
        __syncthreads();                   // As ready (k0=0) / Bs reads done (k0>0)
#pragma unroll
        for (int p = 0; p < 4; ++p) {
            int idx = p * 256 + tid;       // 1024 x 16B chunks
            int n = idx >> 2, c = (idx & 3) * 8;
            *(uint4*)(Bs + n * LDSB + c) = *(const uint4*)(Bt + (size_t)n * 256 + k0 + c);
        }
        __syncthreads();
        short8 af = *(const short8*)(As + lr * LDSA + k0 + lg * 8);
#pragma unroll
        for (int j = 0; j < 4; ++j) {
            short8 bf = *(const short8*)(Bs + (wave * 64 + j * 16 + lr) * LDSB + lg * 8);
            acc[j] = __builtin_amdgcn_mfma_f32_16x16x32_bf16(af, bf, acc[j], 0, 0, 0);
        }
    }

    if (!CHAIN) {
        // epilogue: relu(acc + deg*b) -> bf16 global (625*16 = 10000, no mask)
#pragma unroll
        for (int j = 0; j < 4; ++j) {
            int col = wave * 64 + j * 16 + lr;
            float bv = bias[col];
#pragma unroll
            for (int r = 0; r < 4; ++r) {
                int grow = rowBase + lg * 4 + r;
                float dg = degF[lg * 4 + r];
                Out[(size_t)grow * 256 + col] = f2bf(fmaxf(fmaf(dg, bv, acc[j][r]), 0.f));
            }
        }
    } else {
        __syncthreads();   // all As/Bs reads done before overwrite
        // out2 tile -> As (bf16), cols disjoint per wave
#pragma unroll
        for (int j = 0; j < 4; ++j) {
            int col = wave * 64 + j * 16 + lr;
            float bv = bias[col];
#pragma unroll
            for (int r = 0; r < 4; ++r) {
                int rl = lg * 4 + r;
                As[rl * LDSA + col] = f2bf(fmaxf(fmaf(degF[rl], bv, acc[j][r]), 0.f));
            }
        }
        // stage W3 (40 n-rows x 256 k) into Bs reused as [n][264]: 1280 x 16B chunks
#pragma unroll
        for (int p = 0; p < 5; ++p) {
            int idx = p * 256 + tid;       // 0..1279
            int n = idx >> 5, c = (idx & 31) * 8;
            *(uint4*)(Bs + n * LDSA + c) = *(const uint4*)(W3b + (size_t)n * 256 + c);
        }
        __syncthreads();
        // gemm3: h3 = out2 @ W3 + b3 (waves 0..2 cover 48 cols, mask at 40)
        if (wave < 3) {
            f32x4 acc3 = {};
            for (int k0 = 0; k0 < 256; k0 += 32) {
                short8 af = *(const short8*)(As + lr * LDSA + k0 + lg * 8);
                short8 bf = *(const short8*)(Bs + (wave * 16 + lr) * LDSA + k0 + lg * 8);
                acc3 = __builtin_amdgcn_mfma_f32_16x16x32_bf16(af, bf, acc3, 0, 0, 0);
            }
            int col = wave * 16 + lr;
            if (col < N_CLASSES) {
                float bv = b3[col];
#pragma unroll
                for (int r = 0; r < 4; ++r) {
                    int grow = rowBase + lg * 4 + r;
                    Out[(size_t)grow * N_CLASSES + col] = f2bf(acc3[r] + bv);
                }
            }
        }
    }
}

// ---------------- agg40: out = relu(segsum(h3[src])) -> f32 ----------------

__global__ __launch_bounds__(256)
void agg_relu_40_kernel(const ushort* __restrict__ h, const int* __restrict__ deg,
                        const int* __restrict__ esrc, float* __restrict__ out) {
    int wv   = threadIdx.x >> 6;
    int lane = threadIdx.x & 63;
    int node = (blockIdx.x << 2) + wv;
    if (node >= N_NODES) return;
    int cnt = deg[node];
    if (cnt > CAP) cnt = CAP;
    int cntp = (cnt + 7) & ~7;
    const int* ep = esrc + node * CAP;
    if (lane < N_CLASSES) {
        float a = 0.f, b = 0.f;
#pragma unroll 1
        for (int i = 0; i < cntp; i += 8) {
            int s[8];
#pragma unroll
            for (int u = 0; u < 8; ++u) s[u] = (i + u < cnt) ? ep[i + u] : N_NODES;
#pragma unroll
            for (int u = 0; u < 8; u += 2) {
                a += bf2f(h[(size_t)s[u]     * N_CLASSES + lane]);
                b += bf2f(h[(size_t)s[u + 1] * N_CLASSES + lane]);
            }
        }
        out[(size_t)node * N_CLASSES + lane] = fmaxf(a + b, 0.f);
    }
}

// ---------------- launch ----------------

extern "C" void kernel_launch(void* const* d_in, const int* in_sizes, int n_in,
                              void* d_out, int out_size, void* d_ws, size_t ws_size,
                              hipStream_t stream) {
    const float* X     = (const float*)d_in[0];
    const int*   edges = (const int*)d_in[1];
    const float* W1 = (const float*)d_in[2];
    const float* b1 = (const float*)d_in[3];
    const float* W2 = (const float*)d_in[4];
    const float* b2 = (const float*)d_in[5];
    const float* W3 = (const float*)d_in[6];
    const float* b3 = (const float*)d_in[7];
    float* out = (float*)d_out;

    char* ws = (char*)d_ws;
    ushort* Xb   = (ushort*)(ws);                    //  5,120,512 B (10001 rows x 256)
    ushort* bufY = (ushort*)(ws + 5120512);          //  5,120,512 B (10001 rows)
    ushort* bufH = (ushort*)(ws + 10241024);         //    800,080 B (10001 rows x 40)
    ushort* W1b  = (ushort*)(ws + 11041104);         //    131,072 B (n-major)
    ushort* W2b  = (ushort*)(ws + 11172176);         //    131,072 B
    ushort* W3b  = (ushort*)(ws + 11303248);         //     20,480 B
    int*   cursor = (int*)(ws + 11323728);           //     40,000 B (== deg after place)
    int*   esrc   = (int*)(ws + 11363728);           //  3,840,000 B (10000 x 96)

    // 1: conversions (tiled W transpose) + zero cursor + zero pad rows
    prep_kernel<<<288, 256, 0, stream>>>(X, W1, W2, W3, Xb, bufY, bufH,
                                         W1b, W2b, W3b, cursor);
    // 2: bucket-CSR place
    place_kernel<<<(N_EDGES + 255) / 256, 256, 0, stream>>>(edges, cursor, esrc);
    // 3: layer 1 fused (agg + GEMM + relu)
    layer_kernel<false><<<N_NODES / 16, 256, 0, stream>>>(
        Xb, W1b, b1, cursor, esrc, W3b, b3, bufY);
    // 4: layer 2 fused + chained layer-3 transform (h3 = out2@W3 + b3)
    layer_kernel<true><<<N_NODES / 16, 256, 0, stream>>>(
        bufY, W2b, b2, cursor, esrc, W3b, b3, bufH);
    // 5: final aggregation + relu -> d_out (f32)
    agg_relu_40_kernel<<<(N_NODES + 3) / 4, 256, 0, stream>>>(bufH, cursor, esrc, out);
}

// Round 11
// 170.488 us; speedup vs baseline: 1.0468x; 1.0202x over previous
//
#include <hip/hip_runtime.h>

// NodeClassifier 3-layer MP-GNN, MI355X. R11: split-half gather to fit per-XCD L2.
// Gather table is 5.12MB > 4MiB per-XCD L2 -> thrash (R6: FETCH 28MB/layer from
// a 5MB table). Fix: two passes over edges, channels 0..127 then 128..255;
// per-pass footprint 2.56MB -> L2-resident. 4B/lane loads, identical numerics.
// Also: revert to R7's dummy-filled esrc (clamp-select correlated with the
// R8-R10 regression), keep tiled W transpose + stride-44 Bs (R10).
// 5 dispatches: prep, place, L1 fused, L2 fused + chained L3, agg40.
// agg(x@W+b) == agg(x)@W + deg*b. Lessons: grid.sync ~35us (R3); single-block
// serial work (R4); VGPR-64 cliff + don't force min-waves (R8/R9).

#define N_NODES   10000
#define N_EDGES   320000
#define D_HID     256
#define N_CLASSES 40
#define CAP       96

typedef __attribute__((ext_vector_type(8))) short short8;
typedef __attribute__((ext_vector_type(4))) float f32x4;

__device__ __forceinline__ ushort f2bf(float f) {
    unsigned u = __float_as_uint(f);
    u = (u + 0x7fffu + ((u >> 16) & 1u)) >> 16;   // RNE; inputs finite
    return (ushort)u;
}
__device__ __forceinline__ float bf2f(ushort u) {
    return __uint_as_float(((unsigned)u) << 16);
}

// ---------------- prep ----------------
// Blocks 0..31: coalesced 64x64 LDS-tile transpose of W1/W2 (f32 -> bf16 n-major).
// Blocks 32+: X conversion, W3 transpose, cursor zero, esrc dummy-fill, pad rows.

__global__ __launch_bounds__(256)
void prep_kernel(const float* __restrict__ X,
                 const float* __restrict__ W1, const float* __restrict__ W2,
                 const float* __restrict__ W3,
                 ushort* __restrict__ Xb, ushort* __restrict__ bufY,
                 ushort* __restrict__ bufH,
                 ushort* __restrict__ W1b, ushort* __restrict__ W2b,
                 ushort* __restrict__ W3b, int* __restrict__ cursor,
                 int* __restrict__ esrc) {
    __shared__ float tile[64][65];
    const int tid = threadIdx.x;
    if (blockIdx.x < 32) {
        const float* W  = (blockIdx.x < 16) ? W1 : W2;
        ushort* Wb      = (blockIdx.x < 16) ? W1b : W2b;
        const int b  = blockIdx.x & 15;
        const int k0 = (b >> 2) * 64, n0 = (b & 3) * 64;
        const int lane64 = tid & 63, quad = tid >> 6;
#pragma unroll
        for (int i = 0; i < 16; ++i) {
            int kl = quad + i * 4;
            tile[lane64][kl] = W[(size_t)(k0 + kl) * 256 + n0 + lane64];  // coalesced read
        }
        __syncthreads();
#pragma unroll
        for (int i = 0; i < 16; ++i) {
            int nl = quad + i * 4;
            Wb[(size_t)(n0 + nl) * 256 + k0 + lane64] = f2bf(tile[nl][lane64]);  // coalesced write
        }
        return;
    }
    const int tid0 = (blockIdx.x - 32) * 256 + tid;
    const int nthr = (gridDim.x - 32) * 256;
    for (int i = tid0; i < N_NODES; i += nthr) cursor[i] = 0;
    // dummy-fill all bucket slots with padding node N_NODES (zero row)
    for (int i = tid0; i < N_NODES * CAP; i += nthr) esrc[i] = N_NODES;
    // zero padding rows
    ushort4 z; z.x = 0; z.y = 0; z.z = 0; z.w = 0;
    if (tid0 < 64) {
        ((ushort4*)Xb)[640000 + tid0]   = z;   // row 10000 of Xb
        ((ushort4*)bufY)[640000 + tid0] = z;   // row 10000 of bufY
    }
    if (tid0 < 10) ((ushort4*)bufH)[100000 + tid0] = z;  // row 10000 of bufH
    // X -> bf16
    for (int i = tid0; i < N_NODES * D_HID / 4; i += nthr) {
        float4 v = ((const float4*)X)[i];
        ushort4 o;
        o.x = f2bf(v.x); o.y = f2bf(v.y); o.z = f2bf(v.z); o.w = f2bf(v.w);
        ((ushort4*)Xb)[i] = o;
    }
    // W3 (256x40) -> bf16 n-major (small)
    for (int i = tid0; i < N_CLASSES * 256; i += nthr) {
        int n = i >> 8, k = i & 255;
        W3b[i] = f2bf(W3[(size_t)k * N_CLASSES + n]);
    }
}

// ---------------- place: bucket CSR via global atomics ----------------

__global__ __launch_bounds__(256)
void place_kernel(const int* __restrict__ edges, int* __restrict__ cursor,
                  int* __restrict__ esrc) {
    int e = blockIdx.x * 256 + threadIdx.x;
    if (e < N_EDGES) {
        int d = edges[N_EDGES + e];
        int pos = atomicAdd(&cursor[d], 1);
        if (pos < CAP) esrc[d * CAP + pos] = edges[e];
    }
}

// ---------------- fused layer ----------------
// 256 threads = 4 waves, 16 nodes/block, 625 blocks.
// Phase 1: SPLIT-HALF gather — half 0 (ch 0..127) for all nodes, then half 1.
// Lane loads 4B (2 channels); per-pass L2 footprint 2.56MB (fits 4MiB XCD L2).
// Dummy-padded buckets: no tail, no select. Phase 2: Bs-staged MFMA GEMM.
// CHAIN: out2 tile stays in LDS -> @W3 + b3 -> h3 global (waves 0..2).

#define LDSA 264   // As row stride (bf16)
#define LDSB 44    // Bs row stride (bf16): 22 dwords -> benign bank pattern

template<bool CHAIN>
__global__ __launch_bounds__(256)
void layer_kernel(const ushort* __restrict__ Xin, const ushort* __restrict__ Bt,
                  const float* __restrict__ bias,
                  const int* __restrict__ deg, const int* __restrict__ esrc,
                  const ushort* __restrict__ W3b, const float* __restrict__ b3,
                  ushort* __restrict__ Out) {
    __shared__ ushort As[16 * LDSA];      //  8448 B; x_agg, reused as out2 when CHAIN
    __shared__ ushort Bs[256 * LDSB];     // 22528 B; main: [256 n][44]; chain: W3 [40][264]
    __shared__ int    eidxL[16 * CAP];    //  6144 B
    __shared__ int    degI[16];
    __shared__ float  degF[16];

    const int tid = threadIdx.x;
    const int wave = tid >> 6, lane = tid & 63;
    const int lr = lane & 15, lg = lane >> 4;
    const int rowBase = blockIdx.x * 16;

    // ---- phase 0: stage edge lists + degrees ----
#pragma unroll
    for (int p = 0; p < 6; ++p) {
        int idx = p * 256 + tid;          // 16*96 = 1536 ints
        eidxL[idx] = esrc[rowBase * CAP + idx];
    }
    if (tid < 16) {
        int c = deg[rowBase + tid];
        degF[tid] = (float)c;             // true degree (bias term)
        degI[tid] = (c > CAP) ? CAP : c;
    }
    __syncthreads();

    // ---- phase 1: split-half gather (4 nodes/wave, batches of 8, no tail) ----
    const uint* hp = (const uint*)Xin;    // 4B elems; row stride 128
#pragma unroll 1
    for (int half = 0; half < 2; ++half) {
#pragma unroll 1
        for (int it = 0; it < 4; ++it) {
            int nl = wave * 4 + it;
            const int cntp = (degI[nl] + 7) & ~7;
            float a0 = 0.f, a1 = 0.f;
#pragma unroll 1
            for (int i = 0; i < cntp; i += 8) {
                uint v[8];
#pragma unroll
                for (int u = 0; u < 8; ++u) {
                    int s = eidxL[nl * CAP + i + u];   // LDS broadcast (dummy-padded)
                    v[u] = hp[(size_t)s * 128 + half * 64 + lane];
                }
#pragma unroll
                for (int u = 0; u < 8; ++u) {
                    a0 += bf2f((ushort)(v[u] & 0xffff));
                    a1 += bf2f((ushort)(v[u] >> 16));
                }
            }
            unsigned o = (unsigned)f2bf(a0) | ((unsigned)f2bf(a1) << 16);
            *(unsigned*)(As + nl * LDSA + half * 128 + lane * 2) = o;
        }
    }

    // ---- phase 2: GEMM 16x256 @ 256x256 ----
    f32x4 acc[4] = {};
    for (int k0 = 0; k0 < 256; k0 += 32) {
        __syncthreads();                   // As ready (k0=0) / Bs reads done (k0>0)
#pragma unroll
        for (int p = 0; p < 4; ++p) {
            int idx = p * 256 + tid;       // 1024 x 16B chunks
            int n = idx >> 2, c = (idx & 3) * 8;
            *(uint4*)(Bs + n * LDSB + c) = *(const uint4*)(Bt + (size_t)n * 256 + k0 + c);
        }
        __syncthreads();
        short8 af = *(const short8*)(As + lr * LDSA + k0 + lg * 8);
#pragma unroll
        for (int j = 0; j < 4; ++j) {
            short8 bf = *(const short8*)(Bs + (wave * 64 + j * 16 + lr) * LDSB + lg * 8);
            acc[j] = __builtin_amdgcn_mfma_f32_16x16x32_bf16(af, bf, acc[j], 0, 0, 0);
        }
    }

    if (!CHAIN) {
        // epilogue: relu(acc + deg*b) -> bf16 global (625*16 = 10000, no mask)
#pragma unroll
        for (int j = 0; j < 4; ++j) {
            int col = wave * 64 + j * 16 + lr;
            float bv = bias[col];
#pragma unroll
            for (int r = 0; r < 4; ++r) {
                int grow = rowBase + lg * 4 + r;
                float dg = degF[lg * 4 + r];
                Out[(size_t)grow * 256 + col] = f2bf(fmaxf(fmaf(dg, bv, acc[j][r]), 0.f));
            }
        }
    } else {
        __syncthreads();   // all As/Bs reads done before overwrite
        // out2 tile -> As (bf16), cols disjoint per wave
#pragma unroll
        for (int j = 0; j < 4; ++j) {
            int col = wave * 64 + j * 16 + lr;
            float bv = bias[col];
#pragma unroll
            for (int r = 0; r < 4; ++r) {
                int rl = lg * 4 + r;
                As[rl * LDSA + col] = f2bf(fmaxf(fmaf(degF[rl], bv, acc[j][r]), 0.f));
            }
        }
        // stage W3 (40 n-rows x 256 k) into Bs reused as [n][264]: 1280 x 16B chunks
#pragma unroll
        for (int p = 0; p < 5; ++p) {
            int idx = p * 256 + tid;       // 0..1279
            int n = idx >> 5, c = (idx & 31) * 8;
            *(uint4*)(Bs + n * LDSA + c) = *(const uint4*)(W3b + (size_t)n * 256 + c);
        }
        __syncthreads();
        // gemm3: h3 = out2 @ W3 + b3 (waves 0..2 cover 48 cols, mask at 40)
        if (wave < 3) {
            f32x4 acc3 = {};
            for (int k0 = 0; k0 < 256; k0 += 32) {
                short8 af = *(const short8*)(As + lr * LDSA + k0 + lg * 8);
                short8 bf = *(const short8*)(Bs + (wave * 16 + lr) * LDSA + k0 + lg * 8);
                acc3 = __builtin_amdgcn_mfma_f32_16x16x32_bf16(af, bf, acc3, 0, 0, 0);
            }
            int col = wave * 16 + lr;
            if (col < N_CLASSES) {
                float bv = b3[col];
#pragma unroll
                for (int r = 0; r < 4; ++r) {
                    int grow = rowBase + lg * 4 + r;
                    Out[(size_t)grow * N_CLASSES + col] = f2bf(acc3[r] + bv);
                }
            }
        }
    }
}

// ---------------- agg40: out = relu(segsum(h3[src])) -> f32 ----------------

__global__ __launch_bounds__(256)
void agg_relu_40_kernel(const ushort* __restrict__ h, const int* __restrict__ deg,
                        const int* __restrict__ esrc, float* __restrict__ out) {
    int wv   = threadIdx.x >> 6;
    int lane = threadIdx.x & 63;
    int node = (blockIdx.x << 2) + wv;
    if (node >= N_NODES) return;
    int cnt = deg[node];
    if (cnt > CAP) cnt = CAP;
    int cntp = (cnt + 7) & ~7;            // dummy-padded: no tail
    const int* ep = esrc + node * CAP;
    if (lane < N_CLASSES) {
        float a = 0.f, b = 0.f;
#pragma unroll 1
        for (int i = 0; i < cntp; i += 8) {
            int s[8];
#pragma unroll
            for (int u = 0; u < 8; ++u) s[u] = ep[i + u];
#pragma unroll
            for (int u = 0; u < 8; u += 2) {
                a += bf2f(h[(size_t)s[u]     * N_CLASSES + lane]);
                b += bf2f(h[(size_t)s[u + 1] * N_CLASSES + lane]);
            }
        }
        out[(size_t)node * N_CLASSES + lane] = fmaxf(a + b, 0.f);
    }
}

// ---------------- launch ----------------

extern "C" void kernel_launch(void* const* d_in, const int* in_sizes, int n_in,
                              void* d_out, int out_size, void* d_ws, size_t ws_size,
                              hipStream_t stream) {
    const float* X     = (const float*)d_in[0];
    const int*   edges = (const int*)d_in[1];
    const float* W1 = (const float*)d_in[2];
    const float* b1 = (const float*)d_in[3];
    const float* W2 = (const float*)d_in[4];
    const float* b2 = (const float*)d_in[5];
    const float* W3 = (const float*)d_in[6];
    const float* b3 = (const float*)d_in[7];
    float* out = (float*)d_out;

    char* ws = (char*)d_ws;
    ushort* Xb   = (ushort*)(ws);                    //  5,120,512 B (10001 rows x 256)
    ushort* bufY = (ushort*)(ws + 5120512);          //  5,120,512 B (10001 rows)
    ushort* bufH = (ushort*)(ws + 10241024);         //    800,080 B (10001 rows x 40)
    ushort* W1b  = (ushort*)(ws + 11041104);         //    131,072 B (n-major)
    ushort* W2b  = (ushort*)(ws + 11172176);         //    131,072 B
    ushort* W3b  = (ushort*)(ws + 11303248);         //     20,480 B
    int*   cursor = (int*)(ws + 11323728);           //     40,000 B (== deg after place)
    int*   esrc   = (int*)(ws + 11363728);           //  3,840,000 B (10000 x 96)

    // 1: conversions (tiled W transpose) + cursor zero + esrc dummy-fill + pads
    prep_kernel<<<288, 256, 0, stream>>>(X, W1, W2, W3, Xb, bufY, bufH,
                                         W1b, W2b, W3b, cursor, esrc);
    // 2: bucket-CSR place
    place_kernel<<<(N_EDGES + 255) / 256, 256, 0, stream>>>(edges, cursor, esrc);
    // 3: layer 1 fused (agg + GEMM + relu)
    layer_kernel<false><<<N_NODES / 16, 256, 0, stream>>>(
        Xb, W1b, b1, cursor, esrc, W3b, b3, bufY);
    // 4: layer 2 fused + chained layer-3 transform (h3 = out2@W3 + b3)
    layer_kernel<true><<<N_NODES / 16, 256, 0, stream>>>(
        bufY, W2b, b2, cursor, esrc, W3b, b3, bufH);
    // 5: final aggregation + relu -> d_out (f32)
    agg_relu_40_kernel<<<(N_NODES + 3) / 4, 256, 0, stream>>>(bufH, cursor, esrc, out);
}

// Round 12
// 161.456 us; speedup vs baseline: 1.1054x; 1.0559x over previous
//
#include <hip/hip_runtime.h>

// NodeClassifier 3-layer MP-GNN, MI355X. R12: recombination of proven-best
// pieces. R7 gather (uint2 full-row, batch-8, dummy-padded buckets — every
// deviation R8-R11 regressed) + R10 tiled W transpose + stride-44 Bs.
// 5 dispatches: prep, place, L1 fused, L2 fused + chained L3, agg40.
// agg(x@W+b) == agg(x)@W + deg*b. Lessons: grid.sync ~35us (R3); single-block
// serial work (R4); VGPR-64 cliff / no forced min-waves (R8/R9); clamp-select
// in gather loop costs ~14us (R8-R10); 4B split loads cost ~10us (R11).

#define N_NODES   10000
#define N_EDGES   320000
#define D_HID     256
#define N_CLASSES 40
#define CAP       96

typedef __attribute__((ext_vector_type(8))) short short8;
typedef __attribute__((ext_vector_type(4))) float f32x4;

__device__ __forceinline__ ushort f2bf(float f) {
    unsigned u = __float_as_uint(f);
    u = (u + 0x7fffu + ((u >> 16) & 1u)) >> 16;   // RNE; inputs finite
    return (ushort)u;
}
__device__ __forceinline__ float bf_lo(unsigned v) {   // bf16 in low 16 -> f32
    return __uint_as_float(v << 16);
}
__device__ __forceinline__ float bf_hi(unsigned v) {   // bf16 in high 16 -> f32
    return __uint_as_float(v & 0xffff0000u);
}

// ---------------- prep ----------------
// Blocks 0..31: coalesced 64x64 LDS-tile transpose of W1/W2 (f32 -> bf16 n-major).
// Blocks 32+: X conversion, W3 transpose, cursor zero, esrc dummy-fill, pad rows.

__global__ __launch_bounds__(256)
void prep_kernel(const float* __restrict__ X,
                 const float* __restrict__ W1, const float* __restrict__ W2,
                 const float* __restrict__ W3,
                 ushort* __restrict__ Xb, ushort* __restrict__ bufY,
                 ushort* __restrict__ bufH,
                 ushort* __restrict__ W1b, ushort* __restrict__ W2b,
                 ushort* __restrict__ W3b, int* __restrict__ cursor,
                 int* __restrict__ esrc) {
    __shared__ float tile[64][65];
    const int tid = threadIdx.x;
    if (blockIdx.x < 32) {
        const float* W  = (blockIdx.x < 16) ? W1 : W2;
        ushort* Wb      = (blockIdx.x < 16) ? W1b : W2b;
        const int b  = blockIdx.x & 15;
        const int k0 = (b >> 2) * 64, n0 = (b & 3) * 64;
        const int lane64 = tid & 63, quad = tid >> 6;
#pragma unroll
        for (int i = 0; i < 16; ++i) {
            int kl = quad + i * 4;
            tile[lane64][kl] = W[(size_t)(k0 + kl) * 256 + n0 + lane64];  // coalesced read
        }
        __syncthreads();
#pragma unroll
        for (int i = 0; i < 16; ++i) {
            int nl = quad + i * 4;
            Wb[(size_t)(n0 + nl) * 256 + k0 + lane64] = f2bf(tile[nl][lane64]);  // coalesced write
        }
        return;
    }
    const int tid0 = (blockIdx.x - 32) * 256 + tid;
    const int nthr = (gridDim.x - 32) * 256;
    for (int i = tid0; i < N_NODES; i += nthr) cursor[i] = 0;
    // dummy-fill all bucket slots with padding node N_NODES (zero row)
    for (int i = tid0; i < N_NODES * CAP; i += nthr) esrc[i] = N_NODES;
    // zero padding rows
    ushort4 z; z.x = 0; z.y = 0; z.z = 0; z.w = 0;
    if (tid0 < 64) {
        ((ushort4*)Xb)[640000 + tid0]   = z;   // row 10000 of Xb
        ((ushort4*)bufY)[640000 + tid0] = z;   // row 10000 of bufY
    }
    if (tid0 < 10) ((ushort4*)bufH)[100000 + tid0] = z;  // row 10000 of bufH
    // X -> bf16
    for (int i = tid0; i < N_NODES * D_HID / 4; i += nthr) {
        float4 v = ((const float4*)X)[i];
        ushort4 o;
        o.x = f2bf(v.x); o.y = f2bf(v.y); o.z = f2bf(v.z); o.w = f2bf(v.w);
        ((ushort4*)Xb)[i] = o;
    }
    // W3 (256x40) -> bf16 n-major (small)
    for (int i = tid0; i < N_CLASSES * 256; i += nthr) {
        int n = i >> 8, k = i & 255;
        W3b[i] = f2bf(W3[(size_t)k * N_CLASSES + n]);
    }
}

// ---------------- place: bucket CSR via global atomics ----------------

__global__ __launch_bounds__(256)
void place_kernel(const int* __restrict__ edges, int* __restrict__ cursor,
                  int* __restrict__ esrc) {
    int e = blockIdx.x * 256 + threadIdx.x;
    if (e < N_EDGES) {
        int d = edges[N_EDGES + e];
        int pos = atomicAdd(&cursor[d], 1);
        if (pos < CAP) esrc[d * CAP + pos] = edges[e];
    }
}

// ---------------- fused layer ----------------
// 256 threads = 4 waves, 16 nodes/block, 625 blocks.
// Phase 1: R7 gather — wave-per-node, full 512B row (uint2/lane), batches of 8,
// dummy-padded buckets (no tail, no select). Phase 2: Bs-staged MFMA GEMM,
// stride 44. CHAIN: out2 tile stays in LDS -> @W3 + b3 -> h3 (waves 0..2).

#define LDSA 264   // As row stride (bf16)
#define LDSB 44    // Bs row stride (bf16): 22 dwords -> benign bank pattern

template<bool CHAIN>
__global__ __launch_bounds__(256)
void layer_kernel(const ushort* __restrict__ Xin, const ushort* __restrict__ Bt,
                  const float* __restrict__ bias,
                  const int* __restrict__ deg, const int* __restrict__ esrc,
                  const ushort* __restrict__ W3b, const float* __restrict__ b3,
                  ushort* __restrict__ Out) {
    __shared__ ushort As[16 * LDSA];      //  8448 B; x_agg, reused as out2 when CHAIN
    __shared__ ushort Bs[256 * LDSB];     // 22528 B; main: [256 n][44]; chain: W3 [40][264]
    __shared__ int    eidxL[16 * CAP];    //  6144 B
    __shared__ int    degI[16];
    __shared__ float  degF[16];

    const int tid = threadIdx.x;
    const int wave = tid >> 6, lane = tid & 63;
    const int lr = lane & 15, lg = lane >> 4;
    const int rowBase = blockIdx.x * 16;

    // ---- phase 0: stage edge lists + degrees ----
#pragma unroll
    for (int p = 0; p < 6; ++p) {
        int idx = p * 256 + tid;          // 16*96 = 1536 ints
        eidxL[idx] = esrc[rowBase * CAP + idx];
    }
    if (tid < 16) {
        int c = deg[rowBase + tid];
        degF[tid] = (float)c;             // true degree (bias term)
        degI[tid] = (c > CAP) ? CAP : c;
    }
    __syncthreads();

    // ---- phase 1: gather (4 nodes/wave, batches of 8, dummy-padded) ----
    const uint2* hp = (const uint2*)Xin;
#pragma unroll 1
    for (int it = 0; it < 4; ++it) {
        int nl = wave * 4 + it;
        const int cntp = (degI[nl] + 7) & ~7;
        float a0 = 0.f, a1 = 0.f, a2 = 0.f, a3 = 0.f;
#pragma unroll 1
        for (int i = 0; i < cntp; i += 8) {
            uint2 v[8];
#pragma unroll
            for (int u = 0; u < 8; ++u) {
                int s = eidxL[nl * CAP + i + u];   // LDS broadcast
                v[u] = hp[(size_t)s * 64 + lane];
            }
#pragma unroll
            for (int u = 0; u < 8; ++u) {
                a0 += bf_lo(v[u].x);
                a1 += bf_hi(v[u].x);
                a2 += bf_lo(v[u].y);
                a3 += bf_hi(v[u].y);
            }
        }
        uint2 o;
        o.x = (unsigned)f2bf(a0) | ((unsigned)f2bf(a1) << 16);
        o.y = (unsigned)f2bf(a2) | ((unsigned)f2bf(a3) << 16);
        *(uint2*)(As + nl * LDSA + lane * 4) = o;
    }

    // ---- phase 2: GEMM 16x256 @ 256x256 ----
    f32x4 acc[4] = {};
    for (int k0 = 0; k0 < 256; k0 += 32) {
        __syncthreads();                   // As ready (k0=0) / Bs reads done (k0>0)
#pragma unroll
        for (int p = 0; p < 4; ++p) {
            int idx = p * 256 + tid;       // 1024 x 16B chunks
            int n = idx >> 2, c = (idx & 3) * 8;
            *(uint4*)(Bs + n * LDSB + c) = *(const uint4*)(Bt + (size_t)n * 256 + k0 + c);
        }
        __syncthreads();
        short8 af = *(const short8*)(As + lr * LDSA + k0 + lg * 8);
#pragma unroll
        for (int j = 0; j < 4; ++j) {
            short8 bf = *(const short8*)(Bs + (wave * 64 + j * 16 + lr) * LDSB + lg * 8);
            acc[j] = __builtin_amdgcn_mfma_f32_16x16x32_bf16(af, bf, acc[j], 0, 0, 0);
        }
    }

    if (!CHAIN) {
        // epilogue: relu(acc + deg*b) -> bf16 global (625*16 = 10000, no mask)
#pragma unroll
        for (int j = 0; j < 4; ++j) {
            int col = wave * 64 + j * 16 + lr;
            float bv = bias[col];
#pragma unroll
            for (int r = 0; r < 4; ++r) {
                int grow = rowBase + lg * 4 + r;
                float dg = degF[lg * 4 + r];
                Out[(size_t)grow * 256 + col] = f2bf(fmaxf(fmaf(dg, bv, acc[j][r]), 0.f));
            }
        }
    } else {
        __syncthreads();   // all As/Bs reads done before overwrite
        // out2 tile -> As (bf16), cols disjoint per wave
#pragma unroll
        for (int j = 0; j < 4; ++j) {
            int col = wave * 64 + j * 16 + lr;
            float bv = bias[col];
#pragma unroll
            for (int r = 0; r < 4; ++r) {
                int rl = lg * 4 + r;
                As[rl * LDSA + col] = f2bf(fmaxf(fmaf(degF[rl], bv, acc[j][r]), 0.f));
            }
        }
        // stage W3 (40 n-rows x 256 k) into Bs reused as [n][264]: 1280 x 16B chunks
#pragma unroll
        for (int p = 0; p < 5; ++p) {
            int idx = p * 256 + tid;       // 0..1279
            int n = idx >> 5, c = (idx & 31) * 8;
            *(uint4*)(Bs + n * LDSA + c) = *(const uint4*)(W3b + (size_t)n * 256 + c);
        }
        __syncthreads();
        // gemm3: h3 = out2 @ W3 + b3 (waves 0..2 cover 48 cols, mask at 40)
        if (wave < 3) {
            f32x4 acc3 = {};
            for (int k0 = 0; k0 < 256; k0 += 32) {
                short8 af = *(const short8*)(As + lr * LDSA + k0 + lg * 8);
                short8 bf = *(const short8*)(Bs + (wave * 16 + lr) * LDSA + k0 + lg * 8);
                acc3 = __builtin_amdgcn_mfma_f32_16x16x32_bf16(af, bf, acc3, 0, 0, 0);
            }
            int col = wave * 16 + lr;
            if (col < N_CLASSES) {
                float bv = b3[col];
#pragma unroll
                for (int r = 0; r < 4; ++r) {
                    int grow = rowBase + lg * 4 + r;
                    Out[(size_t)grow * N_CLASSES + col] = f2bf(acc3[r] + bv);
                }
            }
        }
    }
}

// ---------------- agg40: out = relu(segsum(h3[src])) -> f32 ----------------

__global__ __launch_bounds__(256)
void agg_relu_40_kernel(const ushort* __restrict__ h, const int* __restrict__ deg,
                        const int* __restrict__ esrc, float* __restrict__ out) {
    int wv   = threadIdx.x >> 6;
    int lane = threadIdx.x & 63;
    int node = (blockIdx.x << 2) + wv;
    if (node >= N_NODES) return;
    int cnt = deg[node];
    if (cnt > CAP) cnt = CAP;
    int cntp = (cnt + 7) & ~7;            // dummy-padded: no tail
    const int* ep = esrc + node * CAP;
    if (lane < N_CLASSES) {
        float a = 0.f, b = 0.f;
#pragma unroll 1
        for (int i = 0; i < cntp; i += 8) {
            int s[8];
#pragma unroll
            for (int u = 0; u < 8; ++u) s[u] = ep[i + u];
#pragma unroll
            for (int u = 0; u < 8; u += 2) {
                a += __uint_as_float((unsigned)h[(size_t)s[u]     * N_CLASSES + lane] << 16);
                b += __uint_as_float((unsigned)h[(size_t)s[u + 1] * N_CLASSES + lane] << 16);
            }
        }
        out[(size_t)node * N_CLASSES + lane] = fmaxf(a + b, 0.f);
    }
}

// ---------------- launch ----------------

extern "C" void kernel_launch(void* const* d_in, const int* in_sizes, int n_in,
                              void* d_out, int out_size, void* d_ws, size_t ws_size,
                              hipStream_t stream) {
    const float* X     = (const float*)d_in[0];
    const int*   edges = (const int*)d_in[1];
    const float* W1 = (const float*)d_in[2];
    const float* b1 = (const float*)d_in[3];
    const float* W2 = (const float*)d_in[4];
    const float* b2 = (const float*)d_in[5];
    const float* W3 = (const float*)d_in[6];
    const float* b3 = (const float*)d_in[7];
    float* out = (float*)d_out;

    char* ws = (char*)d_ws;
    ushort* Xb   = (ushort*)(ws);                    //  5,120,512 B (10001 rows x 256)
    ushort* bufY = (ushort*)(ws + 5120512);          //  5,120,512 B (10001 rows)
    ushort* bufH = (ushort*)(ws + 10241024);         //    800,080 B (10001 rows x 40)
    ushort* W1b  = (ushort*)(ws + 11041104);         //    131,072 B (n-major)
    ushort* W2b  = (ushort*)(ws + 11172176);         //    131,072 B
    ushort* W3b  = (ushort*)(ws + 11303248);         //     20,480 B
    int*   cursor = (int*)(ws + 11323728);           //     40,000 B (== deg after place)
    int*   esrc   = (int*)(ws + 11363728);           //  3,840,000 B (10000 x 96)

    // 1: conversions (tiled W transpose) + cursor zero + esrc dummy-fill + pads
    prep_kernel<<<288, 256, 0, stream>>>(X, W1, W2, W3, Xb, bufY, bufH,
                                         W1b, W2b, W3b, cursor, esrc);
    // 2: bucket-CSR place
    place_kernel<<<(N_EDGES + 255) / 256, 256, 0, stream>>>(edges, cursor, esrc);
    // 3: layer 1 fused (agg + GEMM + relu)
    layer_kernel<false><<<N_NODES / 16, 256, 0, stream>>>(
        Xb, W1b, b1, cursor, esrc, W3b, b3, bufY);
    // 4: layer 2 fused + chained layer-3 transform (h3 = out2@W3 + b3)
    layer_kernel<true><<<N_NODES / 16, 256, 0, stream>>>(
        bufY, W2b, b2, cursor, esrc, W3b, b3, bufH);
    // 5: final aggregation + relu -> d_out (f32)
    agg_relu_40_kernel<<<(N_NODES + 3) / 4, 256, 0, stream>>>(bufH, cursor, esrc, out);
}